// Round 11
// baseline (249.184 us; speedup 1.0000x reference)
//
#include <hip/hip_runtime.h>

static constexpr float HS3 = 0.35355339059327373f; // (1/sqrt(2))^3

typedef float nfloat4 __attribute__((ext_vector_type(4))); // native vec for NT builtins

// s[m], m = sz*4+sy*2+sx (subband bits); o[p], p = pz*4+py*2+px (parity bits)
__device__ __forceinline__ void ihaar8(const float s[8], float o[8]) {
    float ex[8];
#pragma unroll
    for (int m = 0; m < 8; m += 2) { ex[m] = s[m] + s[m + 1]; ex[m + 1] = s[m] - s[m + 1]; }
    float ey[8];
#pragma unroll
    for (int i = 0; i < 2; ++i)
#pragma unroll
        for (int px = 0; px < 2; ++px) {
            ey[i * 4 + 0 + px] = ex[i * 4 + 0 + px] + ex[i * 4 + 2 + px];
            ey[i * 4 + 2 + px] = ex[i * 4 + 0 + px] - ex[i * 4 + 2 + px];
        }
#pragma unroll
    for (int q = 0; q < 4; ++q) {
        o[q]     = (ey[q] + ey[4 + q]) * HS3;
        o[4 + q] = (ey[q] - ey[4 + q]) * HS3;
    }
}

// one-instruction packed f32->bf16 RNE (gfx950 v_cvt_pk_bf16_f32; no builtin)
__device__ __forceinline__ unsigned int cvt_pk_bf16(float lo, float hi) {
    unsigned int r;
    asm("v_cvt_pk_bf16_f32 %0, %1, %2" : "=v"(r) : "v"(lo), "v"(hi));
    return r;
}
__device__ __forceinline__ float bf2f(unsigned short u) {
    return __uint_as_float((unsigned int)u << 16);
}

// Fully fused 3-level inverse Haar -> vol3 channel-last bf16 [256][256][256][8].
// det2 non-temporal (single-use; keeps vol3 L3-resident for the sampler).
// ld0/v2 time-disjoint -> aliased; 52 KiB LDS -> 3 blocks/CU.
__global__ __launch_bounds__(512) void idwt_fused(const float* __restrict__ approx,
                                                  const float* __restrict__ det0,
                                                  const float* __restrict__ det1,
                                                  const float* __restrict__ det2,
                                                  unsigned short* __restrict__ out) {
    __shared__ __align__(16) unsigned short ld2[56 * 256]; // det2 tile (bf16)    28 KiB
    __shared__ __align__(16) float ld1[56 * 64];           // det1 row            14 KiB
    __shared__ __align__(16) float ld0v2[16 * 128];        // ld0 (64x32) / v2 (16x128) 8 KiB
    __shared__ __align__(16) float v1[8 * 64];             // vol1 row             2 KiB

    float* const ld0 = ld0v2; // [64][32] view, dead after L0 phase
    float* const v2  = ld0v2; // [16][128] view, live from L1 phase

    const int R3_2 = 128 * 128 * 128;
    const int R3_1 = 64 * 64 * 64;
    const int R3_0 = 32 * 32 * 32;

    int blk = blockIdx.x;          // 8192 blocks
    int Z = blk >> 6;              // 0..127 (L2 cell z)
    int k = blk & 63;              // y-pair: cells cover Y in {2k, 2k+1}
    int T0 = Z * 16384 + k * 256;  // base cell id in 128^3 linear
    int t = threadIdx.x;
    int wave = t >> 6, lane = t & 63;

    // ---- stage det2 (non-temporal): waves 0-6, 8 streams each; f32->bf16 via cvt_pk
    if (wave < 7) {
        uint2* ld2u2 = reinterpret_cast<uint2*>(ld2); // [56][64] uint2
#pragma unroll
        for (int q = 0; q < 8; ++q) {
            int s = wave * 8 + q;
            nfloat4 v = __builtin_nontemporal_load(
                reinterpret_cast<const nfloat4*>(det2 + (size_t)s * R3_2 + T0) + lane);
            uint2 pkd;
            pkd.x = cvt_pk_bf16(v.x, v.y);
            pkd.y = cvt_pk_bf16(v.z, v.w);
            ld2u2[s * 64 + lane] = pkd;
        }
    }
    // ---- stage det1 row (cz = Z>>1, cy = k): 56 streams x 64 floats = 896 float4
    {
        int cz = Z >> 1, cy = k;
        size_t rowoff = (size_t)cz * 4096 + (size_t)cy * 64;
        float4* d = reinterpret_cast<float4*>(ld1);
        {
            int s = t >> 4, f = t & 15;
            d[t] = reinterpret_cast<const float4*>(det1 + (size_t)s * R3_1 + rowoff)[f];
        }
        if (t < 384) {
            int idx = t + 512;
            int s = idx >> 4, f = idx & 15;
            d[idx] = reinterpret_cast<const float4*>(det1 + (size_t)s * R3_1 + rowoff)[f];
        }
    }
    // ---- stage approx+det0 row (z0 = Z>>2, y0 = k>>1): 64 streams x 32 floats
    {
        int z0 = Z >> 2, y0 = k >> 1;
        int s = t >> 3, f = t & 7;
        const float* base = (s < 8) ? (approx + (size_t)s * R3_0) : (det0 + (size_t)(s - 8) * R3_0);
        reinterpret_cast<float4*>(ld0)[t] = reinterpret_cast<const float4*>(base + z0 * 1024 + y0 * 32)[f];
    }
    __syncthreads();

    // ---- L0: 8ch x 32 cells; keep parity (pz0,py0), both px
    if (t < 256) {
        int c = t >> 5, x0 = t & 31;
        float s8[8];
        s8[0] = ld0[c * 32 + x0];
#pragma unroll
        for (int bb = 0; bb < 7; ++bb) s8[bb + 1] = ld0[(8 + bb * 8 + c) * 32 + x0];
        float o[8];
        ihaar8(s8, o);
        int pz0 = (Z >> 1) & 1, py0 = k & 1;
        v1[c * 64 + 2 * x0 + 0] = o[pz0 * 4 + py0 * 2 + 0];
        v1[c * 64 + 2 * x0 + 1] = o[pz0 * 4 + py0 * 2 + 1];
    }
    __syncthreads(); // after this barrier ld0 is dead; v2 may overwrite it

    // ---- L1: 8ch x 64 cells; keep pz1 = Z&1, both py, both px
    {
        int c = t >> 6, x1 = t & 63;
        float s8[8];
        s8[0] = v1[c * 64 + x1];
#pragma unroll
        for (int bb = 0; bb < 7; ++bb) s8[bb + 1] = ld1[(bb * 8 + c) * 64 + x1];
        float o[8];
        ihaar8(s8, o);
        int pz1 = Z & 1;
#pragma unroll
        for (int py = 0; py < 2; ++py)
#pragma unroll
            for (int px = 0; px < 2; ++px)
                v2[(c * 2 + py) * 128 + 2 * x1 + px] = o[pz1 * 4 + py * 2 + px];
    }
    __syncthreads();

    // ---- L2 + bf16 channel-last store (cell = t>>1, h = t&1 -> contiguous 512B wave stores)
    int cell = t >> 1, h = t & 1;
    int cid = T0 + cell;
    int Y = (cid >> 7) & 127, X = cid & 127;
    int yb = cell >> 7;

    float ob[8][4]; // [parity][cc]
#pragma unroll
    for (int cc = 0; cc < 4; ++cc) {
        int c = h * 4 + cc;
        float s8[8];
        s8[0] = v2[(c * 2 + yb) * 128 + X];
#pragma unroll
        for (int bb = 0; bb < 7; ++bb) s8[bb + 1] = bf2f(ld2[(bb * 8 + c) * 256 + cell]);
        float o[8];
        ihaar8(s8, o);
#pragma unroll
        for (int p = 0; p < 8; ++p) ob[p][cc] = o[p];
    }

    uint2* out2 = reinterpret_cast<uint2*>(out);
#pragma unroll
    for (int pz = 0; pz < 2; ++pz)
#pragma unroll
        for (int py = 0; py < 2; ++py)
#pragma unroll
            for (int px = 0; px < 2; ++px) {
                int p = pz * 4 + py * 2 + px;
                size_t vox = (((size_t)(2 * Z + pz) * 256 + (2 * Y + py)) * 256 + (2 * X + px));
                uint2 v;
                v.x = cvt_pk_bf16(ob[p][0], ob[p][1]);
                v.y = cvt_pk_bf16(ob[p][2], ob[p][3]);
                out2[vox * 2 + h] = v;
            }
}

__device__ __forceinline__ float map_grid(float v) {
    float g = (v * (1.0f / 1.5f) + 1.0f) * (0.5f * 255.0f);
    return fminf(fmaxf(g, 0.0f), 255.0f);
}

__global__ void sample_kernel(const float* __restrict__ xyz, const unsigned short* __restrict__ vol,
                              float* __restrict__ out, int N) {
    int i = blockIdx.x * blockDim.x + threadIdx.x;
    if (i >= N) return;
    float gx = map_grid(__builtin_nontemporal_load(xyz + 3 * i + 0));
    float gy = map_grid(__builtin_nontemporal_load(xyz + 3 * i + 1));
    float gz = map_grid(__builtin_nontemporal_load(xyz + 3 * i + 2));
    float x0f = floorf(gx), y0f = floorf(gy), z0f = floorf(gz);
    int x0 = (int)x0f, y0 = (int)y0f, z0 = (int)z0f;
    float fx = gx - x0f, fy = gy - y0f, fz = gz - z0f;
    int x1 = min(x0 + 1, 255), y1 = min(y0 + 1, 255), z1 = min(z0 + 1, 255);
    float wx0 = 1.0f - fx, wy0 = 1.0f - fy, wz0 = 1.0f - fz;

    float acc[8];
#pragma unroll
    for (int kk = 0; kk < 8; ++kk) acc[kk] = 0.0f;

    auto corner = [&](int z, int y, int x, float w) {
        const uint4* v4 = reinterpret_cast<const uint4*>(vol + ((((size_t)z * 256 + y) * 256 + x) << 3));
        uint4 a = *v4; // 8 bf16
        acc[0] += w * __uint_as_float(a.x << 16);
        acc[1] += w * __uint_as_float(a.x & 0xFFFF0000u);
        acc[2] += w * __uint_as_float(a.y << 16);
        acc[3] += w * __uint_as_float(a.y & 0xFFFF0000u);
        acc[4] += w * __uint_as_float(a.z << 16);
        acc[5] += w * __uint_as_float(a.z & 0xFFFF0000u);
        acc[6] += w * __uint_as_float(a.w << 16);
        acc[7] += w * __uint_as_float(a.w & 0xFFFF0000u);
    };
    corner(z0, y0, x0, wz0 * wy0 * wx0);
    corner(z0, y0, x1, wz0 * wy0 * fx);
    corner(z0, y1, x0, wz0 * fy * wx0);
    corner(z0, y1, x1, wz0 * fy * fx);
    corner(z1, y0, x0, fz * wy0 * wx0);
    corner(z1, y0, x1, fz * wy0 * fx);
    corner(z1, y1, x0, fz * fy * wx0);
    corner(z1, y1, x1, fz * fy * fx);

    nfloat4 o0 = {acc[0], acc[1], acc[2], acc[3]};
    nfloat4 o1 = {acc[4], acc[5], acc[6], acc[7]};
    nfloat4* o4 = reinterpret_cast<nfloat4*>(out + (size_t)i * 8);
    __builtin_nontemporal_store(o0, o4);
    __builtin_nontemporal_store(o1, o4 + 1);
}

extern "C" void kernel_launch(void* const* d_in, const int* in_sizes, int n_in,
                              void* d_out, int out_size, void* d_ws, size_t ws_size,
                              hipStream_t stream) {
    const float* xyz     = (const float*)d_in[0];
    const float* approx  = (const float*)d_in[1];
    const float* detail0 = (const float*)d_in[2];
    const float* detail1 = (const float*)d_in[3];
    const float* detail2 = (const float*)d_in[4];
    float* out = (float*)d_out;
    int N = in_sizes[0] / 3;

    unsigned short* vol3 = (unsigned short*)d_ws; // 256^3 * 8 bf16 = 256 MiB

    // Fused 3-level inverse wavelet -> channel-last bf16 volume
    idwt_fused<<<8192, 512, 0, stream>>>(approx, detail0, detail1, detail2, vol3);
    // Trilinear sampling
    sample_kernel<<<(N + 255) / 256, 256, 0, stream>>>(xyz, vol3, out, N);
}

// Round 12
// 236.043 us; speedup vs baseline: 1.0557x; 1.0557x over previous
//
#include <hip/hip_runtime.h>

static constexpr float HS3 = 0.35355339059327373f; // (1/sqrt(2))^3

typedef float nfloat4 __attribute__((ext_vector_type(4))); // native vec for NT builtins

// s[m], m = sz*4+sy*2+sx (subband bits); o[p], p = pz*4+py*2+px (parity bits)
__device__ __forceinline__ void ihaar8(const float s[8], float o[8]) {
    float ex[8];
#pragma unroll
    for (int m = 0; m < 8; m += 2) { ex[m] = s[m] + s[m + 1]; ex[m + 1] = s[m] - s[m + 1]; }
    float ey[8];
#pragma unroll
    for (int i = 0; i < 2; ++i)
#pragma unroll
        for (int px = 0; px < 2; ++px) {
            ey[i * 4 + 0 + px] = ex[i * 4 + 0 + px] + ex[i * 4 + 2 + px];
            ey[i * 4 + 2 + px] = ex[i * 4 + 0 + px] - ex[i * 4 + 2 + px];
        }
#pragma unroll
    for (int q = 0; q < 4; ++q) {
        o[q]     = (ey[q] + ey[4 + q]) * HS3;
        o[4 + q] = (ey[q] - ey[4 + q]) * HS3;
    }
}

__device__ __forceinline__ unsigned short f2bf(float f) {
    unsigned int u = __float_as_uint(f);
    unsigned int r = (u + 0x7FFFu + ((u >> 16) & 1u)) >> 16; // RNE
    return (unsigned short)r;
}
__device__ __forceinline__ unsigned int pk2bf(float lo, float hi) {
    return (unsigned int)f2bf(lo) | ((unsigned int)f2bf(hi) << 16);
}
__device__ __forceinline__ float bf2f(unsigned short u) {
    return __uint_as_float((unsigned int)u << 16);
}

// Fully fused 3-level inverse Haar -> vol3 channel-last bf16 [256][256][256][8].
// det2 non-temporal (single-use; keeps vol3 L3-resident for the sampler).
// ALL staged data bf16 in LDS: ld2 28K + ld1 7K + (ld0|v2 alias) 4K + v1 1K
// = exactly 40 KiB -> 4 blocks/CU (32 waves/CU, max occupancy).
__global__ __launch_bounds__(512) void idwt_fused(const float* __restrict__ approx,
                                                  const float* __restrict__ det0,
                                                  const float* __restrict__ det1,
                                                  const float* __restrict__ det2,
                                                  unsigned short* __restrict__ out) {
    __shared__ __align__(16) unsigned short ld2[56 * 256]; // det2 tile bf16   28 KiB
    __shared__ __align__(16) unsigned short ld1[56 * 64];  // det1 row bf16     7 KiB
    __shared__ __align__(16) unsigned short ld0v2[2048];   // ld0[64*32] / v2[16*128] 4 KiB
    __shared__ __align__(16) unsigned short v1[8 * 64];    // vol1 row bf16     1 KiB

    const int R3_2 = 128 * 128 * 128;
    const int R3_1 = 64 * 64 * 64;
    const int R3_0 = 32 * 32 * 32;

    int blk = blockIdx.x;          // 8192 blocks
    int Z = blk >> 6;              // 0..127 (L2 cell z)
    int k = blk & 63;              // y-pair: cells cover Y in {2k, 2k+1}
    int T0 = Z * 16384 + k * 256;  // base cell id in 128^3 linear
    int t = threadIdx.x;
    int wave = t >> 6, lane = t & 63;

    // ---- stage det2 (non-temporal): waves 0-6, 8 streams each; f32->bf16
    if (wave < 7) {
        uint2* ld2u2 = reinterpret_cast<uint2*>(ld2); // [56][64] uint2
#pragma unroll
        for (int q = 0; q < 8; ++q) {
            int s = wave * 8 + q;
            nfloat4 v = __builtin_nontemporal_load(
                reinterpret_cast<const nfloat4*>(det2 + (size_t)s * R3_2 + T0) + lane);
            uint2 pkd;
            pkd.x = pk2bf(v.x, v.y);
            pkd.y = pk2bf(v.z, v.w);
            ld2u2[s * 64 + lane] = pkd;
        }
    }
    // ---- stage det1 row bf16 (cz = Z>>1, cy = k): 56 streams x 64 floats = 896 float4
    {
        int cz = Z >> 1, cy = k;
        size_t rowoff = (size_t)cz * 4096 + (size_t)cy * 64;
        uint2* d = reinterpret_cast<uint2*>(ld1); // [56][16] uint2
        {
            int s = t >> 4, f = t & 15;
            float4 v = reinterpret_cast<const float4*>(det1 + (size_t)s * R3_1 + rowoff)[f];
            d[t] = make_uint2(pk2bf(v.x, v.y), pk2bf(v.z, v.w));
        }
        if (t < 384) {
            int idx = t + 512;
            int s = idx >> 4, f = idx & 15;
            float4 v = reinterpret_cast<const float4*>(det1 + (size_t)s * R3_1 + rowoff)[f];
            d[idx] = make_uint2(pk2bf(v.x, v.y), pk2bf(v.z, v.w));
        }
    }
    // ---- stage approx+det0 row bf16 (z0 = Z>>2, y0 = k>>1): 64 streams x 32 floats
    {
        int z0 = Z >> 2, y0 = k >> 1;
        int s = t >> 3, f = t & 7;
        const float* base = (s < 8) ? (approx + (size_t)s * R3_0) : (det0 + (size_t)(s - 8) * R3_0);
        float4 v = reinterpret_cast<const float4*>(base + z0 * 1024 + y0 * 32)[f];
        reinterpret_cast<uint2*>(ld0v2)[t] = make_uint2(pk2bf(v.x, v.y), pk2bf(v.z, v.w));
    }
    __syncthreads();

    // ---- L0: 8ch x 32 cells; keep parity (pz0,py0), both px
    if (t < 256) {
        int c = t >> 5, x0 = t & 31;
        float s8[8];
        s8[0] = bf2f(ld0v2[c * 32 + x0]);
#pragma unroll
        for (int bb = 0; bb < 7; ++bb) s8[bb + 1] = bf2f(ld0v2[(8 + bb * 8 + c) * 32 + x0]);
        float o[8];
        ihaar8(s8, o);
        int pz0 = (Z >> 1) & 1, py0 = k & 1;
        reinterpret_cast<unsigned int*>(v1)[c * 32 + x0] =
            pk2bf(o[pz0 * 4 + py0 * 2 + 0], o[pz0 * 4 + py0 * 2 + 1]);
    }
    __syncthreads(); // ld0 view of ld0v2 dead; v2 view may overwrite

    // ---- L1: 8ch x 64 cells; keep pz1 = Z&1, both py, both px
    {
        int c = t >> 6, x1 = t & 63;
        float s8[8];
        s8[0] = bf2f(v1[c * 64 + x1]);
#pragma unroll
        for (int bb = 0; bb < 7; ++bb) s8[bb + 1] = bf2f(ld1[(bb * 8 + c) * 64 + x1]);
        float o[8];
        ihaar8(s8, o);
        int pz1 = Z & 1;
        unsigned int* v2u = reinterpret_cast<unsigned int*>(ld0v2); // [16][64] uint
#pragma unroll
        for (int py = 0; py < 2; ++py)
            v2u[(c * 2 + py) * 64 + x1] =
                pk2bf(o[pz1 * 4 + py * 2 + 0], o[pz1 * 4 + py * 2 + 1]);
    }
    __syncthreads();

    // ---- L2 + bf16 channel-last store (cell = t>>1, h = t&1 -> contiguous 512B wave stores)
    int cell = t >> 1, h = t & 1;
    int cid = T0 + cell;
    int Y = (cid >> 7) & 127, X = cid & 127;
    int yb = cell >> 7;

    float ob[8][4]; // [parity][cc]
#pragma unroll
    for (int cc = 0; cc < 4; ++cc) {
        int c = h * 4 + cc;
        float s8[8];
        s8[0] = bf2f(ld0v2[(c * 2 + yb) * 128 + X]); // v2 view
#pragma unroll
        for (int bb = 0; bb < 7; ++bb) s8[bb + 1] = bf2f(ld2[(bb * 8 + c) * 256 + cell]);
        float o[8];
        ihaar8(s8, o);
#pragma unroll
        for (int p = 0; p < 8; ++p) ob[p][cc] = o[p];
    }

    uint2* out2 = reinterpret_cast<uint2*>(out);
#pragma unroll
    for (int pz = 0; pz < 2; ++pz)
#pragma unroll
        for (int py = 0; py < 2; ++py)
#pragma unroll
            for (int px = 0; px < 2; ++px) {
                int p = pz * 4 + py * 2 + px;
                size_t vox = (((size_t)(2 * Z + pz) * 256 + (2 * Y + py)) * 256 + (2 * X + px));
                uint2 v;
                v.x = pk2bf(ob[p][0], ob[p][1]);
                v.y = pk2bf(ob[p][2], ob[p][3]);
                out2[vox * 2 + h] = v;
            }
}

__device__ __forceinline__ float map_grid(float v) {
    float g = (v * (1.0f / 1.5f) + 1.0f) * (0.5f * 255.0f);
    return fminf(fmaxf(g, 0.0f), 255.0f);
}

__global__ void sample_kernel(const float* __restrict__ xyz, const unsigned short* __restrict__ vol,
                              float* __restrict__ out, int N) {
    int i = blockIdx.x * blockDim.x + threadIdx.x;
    if (i >= N) return;
    float gx = map_grid(__builtin_nontemporal_load(xyz + 3 * i + 0));
    float gy = map_grid(__builtin_nontemporal_load(xyz + 3 * i + 1));
    float gz = map_grid(__builtin_nontemporal_load(xyz + 3 * i + 2));
    float x0f = floorf(gx), y0f = floorf(gy), z0f = floorf(gz);
    int x0 = (int)x0f, y0 = (int)y0f, z0 = (int)z0f;
    float fx = gx - x0f, fy = gy - y0f, fz = gz - z0f;
    int x1 = min(x0 + 1, 255), y1 = min(y0 + 1, 255), z1 = min(z0 + 1, 255);
    float wx0 = 1.0f - fx, wy0 = 1.0f - fy, wz0 = 1.0f - fz;

    float acc[8];
#pragma unroll
    for (int kk = 0; kk < 8; ++kk) acc[kk] = 0.0f;

    auto corner = [&](int z, int y, int x, float w) {
        const uint4* v4 = reinterpret_cast<const uint4*>(vol + ((((size_t)z * 256 + y) * 256 + x) << 3));
        uint4 a = *v4; // 8 bf16
        acc[0] += w * __uint_as_float(a.x << 16);
        acc[1] += w * __uint_as_float(a.x & 0xFFFF0000u);
        acc[2] += w * __uint_as_float(a.y << 16);
        acc[3] += w * __uint_as_float(a.y & 0xFFFF0000u);
        acc[4] += w * __uint_as_float(a.z << 16);
        acc[5] += w * __uint_as_float(a.z & 0xFFFF0000u);
        acc[6] += w * __uint_as_float(a.w << 16);
        acc[7] += w * __uint_as_float(a.w & 0xFFFF0000u);
    };
    corner(z0, y0, x0, wz0 * wy0 * wx0);
    corner(z0, y0, x1, wz0 * wy0 * fx);
    corner(z0, y1, x0, wz0 * fy * wx0);
    corner(z0, y1, x1, wz0 * fy * fx);
    corner(z1, y0, x0, fz * wy0 * wx0);
    corner(z1, y0, x1, fz * wy0 * fx);
    corner(z1, y1, x0, fz * fy * wx0);
    corner(z1, y1, x1, fz * fy * fx);

    nfloat4 o0 = {acc[0], acc[1], acc[2], acc[3]};
    nfloat4 o1 = {acc[4], acc[5], acc[6], acc[7]};
    nfloat4* o4 = reinterpret_cast<nfloat4*>(out + (size_t)i * 8);
    __builtin_nontemporal_store(o0, o4);
    __builtin_nontemporal_store(o1, o4 + 1);
}

extern "C" void kernel_launch(void* const* d_in, const int* in_sizes, int n_in,
                              void* d_out, int out_size, void* d_ws, size_t ws_size,
                              hipStream_t stream) {
    const float* xyz     = (const float*)d_in[0];
    const float* approx  = (const float*)d_in[1];
    const float* detail0 = (const float*)d_in[2];
    const float* detail1 = (const float*)d_in[3];
    const float* detail2 = (const float*)d_in[4];
    float* out = (float*)d_out;
    int N = in_sizes[0] / 3;

    unsigned short* vol3 = (unsigned short*)d_ws; // 256^3 * 8 bf16 = 256 MiB

    // Fused 3-level inverse wavelet -> channel-last bf16 volume
    idwt_fused<<<8192, 512, 0, stream>>>(approx, detail0, detail1, detail2, vol3);
    // Trilinear sampling
    sample_kernel<<<(N + 255) / 256, 256, 0, stream>>>(xyz, vol3, out, N);
}

// Round 13
// 234.967 us; speedup vs baseline: 1.0605x; 1.0046x over previous
//
#include <hip/hip_runtime.h>

static constexpr float HS3 = 0.35355339059327373f; // (1/sqrt(2))^3

typedef float nfloat4 __attribute__((ext_vector_type(4))); // native vec for NT builtins

// s[m], m = sz*4+sy*2+sx (subband bits); o[p], p = pz*4+py*2+px (parity bits)
__device__ __forceinline__ void ihaar8(const float s[8], float o[8]) {
    float ex[8];
#pragma unroll
    for (int m = 0; m < 8; m += 2) { ex[m] = s[m] + s[m + 1]; ex[m + 1] = s[m] - s[m + 1]; }
    float ey[8];
#pragma unroll
    for (int i = 0; i < 2; ++i)
#pragma unroll
        for (int px = 0; px < 2; ++px) {
            ey[i * 4 + 0 + px] = ex[i * 4 + 0 + px] + ex[i * 4 + 2 + px];
            ey[i * 4 + 2 + px] = ex[i * 4 + 0 + px] - ex[i * 4 + 2 + px];
        }
#pragma unroll
    for (int q = 0; q < 4; ++q) {
        o[q]     = (ey[q] + ey[4 + q]) * HS3;
        o[4 + q] = (ey[q] - ey[4 + q]) * HS3;
    }
}

__device__ __forceinline__ unsigned short f2bf(float f) {
    unsigned int u = __float_as_uint(f);
    unsigned int r = (u + 0x7FFFu + ((u >> 16) & 1u)) >> 16; // RNE
    return (unsigned short)r;
}
__device__ __forceinline__ unsigned int pk2bf(float lo, float hi) {
    return (unsigned int)f2bf(lo) | ((unsigned int)f2bf(hi) << 16);
}
__device__ __forceinline__ float bf2f(unsigned short u) {
    return __uint_as_float((unsigned int)u << 16);
}

// Fully fused 3-level inverse Haar -> vol3 bf16, 2x2x2-BRICK layout:
// brick b = L2 cell cid (128^3 bricks), 128 B = [pz][py][px][c0..7] bf16.
// det2 non-temporal (single-use; keeps vol3 L3-resident for the sampler).
// LDS all-bf16: 28K + 7K + 4K(alias) + 1K = 40 KiB -> 4 blocks/CU.
__global__ __launch_bounds__(512) void idwt_fused(const float* __restrict__ approx,
                                                  const float* __restrict__ det0,
                                                  const float* __restrict__ det1,
                                                  const float* __restrict__ det2,
                                                  unsigned short* __restrict__ out) {
    __shared__ __align__(16) unsigned short ld2[56 * 256]; // det2 tile bf16   28 KiB
    __shared__ __align__(16) unsigned short ld1[56 * 64];  // det1 row bf16     7 KiB
    __shared__ __align__(16) unsigned short ld0v2[2048];   // ld0[64*32] / v2[16*128] 4 KiB
    __shared__ __align__(16) unsigned short v1[8 * 64];    // vol1 row bf16     1 KiB

    const int R3_2 = 128 * 128 * 128;
    const int R3_1 = 64 * 64 * 64;
    const int R3_0 = 32 * 32 * 32;

    int blk = blockIdx.x;          // 8192 blocks
    int Z = blk >> 6;              // 0..127 (L2 cell z)
    int k = blk & 63;              // y-pair: cells cover Y in {2k, 2k+1}
    int T0 = Z * 16384 + k * 256;  // base cell id in 128^3 linear
    int t = threadIdx.x;

    // ---- stage det2 (non-temporal, ALL 8 waves, 7 float4 each): f32->bf16
    {
        uint2* ld2u2 = reinterpret_cast<uint2*>(ld2); // [56][64] uint2
#pragma unroll
        for (int q = 0; q < 7; ++q) {
            int idx = q * 512 + t;
            int s = idx >> 6, lane = idx & 63;
            nfloat4 v = __builtin_nontemporal_load(
                reinterpret_cast<const nfloat4*>(det2 + (size_t)s * R3_2 + T0) + lane);
            uint2 pkd;
            pkd.x = pk2bf(v.x, v.y);
            pkd.y = pk2bf(v.z, v.w);
            ld2u2[s * 64 + lane] = pkd;
        }
    }
    // ---- stage det1 row bf16 (cz = Z>>1, cy = k): 56 streams x 64 floats = 896 float4
    {
        int cz = Z >> 1, cy = k;
        size_t rowoff = (size_t)cz * 4096 + (size_t)cy * 64;
        uint2* d = reinterpret_cast<uint2*>(ld1); // [56][16] uint2
        {
            int s = t >> 4, f = t & 15;
            float4 v = reinterpret_cast<const float4*>(det1 + (size_t)s * R3_1 + rowoff)[f];
            d[t] = make_uint2(pk2bf(v.x, v.y), pk2bf(v.z, v.w));
        }
        if (t < 384) {
            int idx = t + 512;
            int s = idx >> 4, f = idx & 15;
            float4 v = reinterpret_cast<const float4*>(det1 + (size_t)s * R3_1 + rowoff)[f];
            d[idx] = make_uint2(pk2bf(v.x, v.y), pk2bf(v.z, v.w));
        }
    }
    // ---- stage approx+det0 row bf16 (z0 = Z>>2, y0 = k>>1): 64 streams x 32 floats
    {
        int z0 = Z >> 2, y0 = k >> 1;
        int s = t >> 3, f = t & 7;
        const float* base = (s < 8) ? (approx + (size_t)s * R3_0) : (det0 + (size_t)(s - 8) * R3_0);
        float4 v = reinterpret_cast<const float4*>(base + z0 * 1024 + y0 * 32)[f];
        reinterpret_cast<uint2*>(ld0v2)[t] = make_uint2(pk2bf(v.x, v.y), pk2bf(v.z, v.w));
    }
    __syncthreads();

    // ---- L0: 8ch x 32 cells; keep parity (pz0,py0), both px
    if (t < 256) {
        int c = t >> 5, x0 = t & 31;
        float s8[8];
        s8[0] = bf2f(ld0v2[c * 32 + x0]);
#pragma unroll
        for (int bb = 0; bb < 7; ++bb) s8[bb + 1] = bf2f(ld0v2[(8 + bb * 8 + c) * 32 + x0]);
        float o[8];
        ihaar8(s8, o);
        int pz0 = (Z >> 1) & 1, py0 = k & 1;
        reinterpret_cast<unsigned int*>(v1)[c * 32 + x0] =
            pk2bf(o[pz0 * 4 + py0 * 2 + 0], o[pz0 * 4 + py0 * 2 + 1]);
    }
    __syncthreads(); // ld0 view of ld0v2 dead; v2 view may overwrite

    // ---- L1: 8ch x 64 cells; keep pz1 = Z&1, both py, both px
    {
        int c = t >> 6, x1 = t & 63;
        float s8[8];
        s8[0] = bf2f(v1[c * 64 + x1]);
#pragma unroll
        for (int bb = 0; bb < 7; ++bb) s8[bb + 1] = bf2f(ld1[(bb * 8 + c) * 64 + x1]);
        float o[8];
        ihaar8(s8, o);
        int pz1 = Z & 1;
        unsigned int* v2u = reinterpret_cast<unsigned int*>(ld0v2); // [16][64] uint
#pragma unroll
        for (int py = 0; py < 2; ++py)
            v2u[(c * 2 + py) * 64 + x1] =
                pk2bf(o[pz1 * 4 + py * 2 + 0], o[pz1 * 4 + py * 2 + 1]);
    }
    __syncthreads();

    // ---- L2 + brick store: brick cid = T0+cell, 16 uint2; voxel p at slot p*2+h
    int cell = t >> 1, h = t & 1;
    int cid = T0 + cell;
    int X = cid & 127;
    int yb = cell >> 7;

    float ob[8][4]; // [parity][cc]
#pragma unroll
    for (int cc = 0; cc < 4; ++cc) {
        int c = h * 4 + cc;
        float s8[8];
        s8[0] = bf2f(ld0v2[(c * 2 + yb) * 128 + X]); // v2 view
#pragma unroll
        for (int bb = 0; bb < 7; ++bb) s8[bb + 1] = bf2f(ld2[(bb * 8 + c) * 256 + cell]);
        float o[8];
        ihaar8(s8, o);
#pragma unroll
        for (int p = 0; p < 8; ++p) ob[p][cc] = o[p];
    }

    uint2* out2 = reinterpret_cast<uint2*>(out);
    size_t bbase = (size_t)cid * 16 + h;
#pragma unroll
    for (int p = 0; p < 8; ++p) {
        uint2 v;
        v.x = pk2bf(ob[p][0], ob[p][1]);
        v.y = pk2bf(ob[p][2], ob[p][3]);
        out2[bbase + p * 2] = v;
    }
}

__device__ __forceinline__ float map_grid(float v) {
    float g = (v * (1.0f / 1.5f) + 1.0f) * (0.5f * 255.0f);
    return fminf(fmaxf(g, 0.0f), 255.0f);
}

__global__ void sample_kernel(const float* __restrict__ xyz, const unsigned short* __restrict__ vol,
                              float* __restrict__ out, int N) {
    int i = blockIdx.x * blockDim.x + threadIdx.x;
    if (i >= N) return;
    float gx = map_grid(__builtin_nontemporal_load(xyz + 3 * i + 0));
    float gy = map_grid(__builtin_nontemporal_load(xyz + 3 * i + 1));
    float gz = map_grid(__builtin_nontemporal_load(xyz + 3 * i + 2));
    float x0f = floorf(gx), y0f = floorf(gy), z0f = floorf(gz);
    int x0 = (int)x0f, y0 = (int)y0f, z0 = (int)z0f;
    float fx = gx - x0f, fy = gy - y0f, fz = gz - z0f;
    int x1 = min(x0 + 1, 255), y1 = min(y0 + 1, 255), z1 = min(z0 + 1, 255);
    float wx0 = 1.0f - fx, wy0 = 1.0f - fy, wz0 = 1.0f - fz;

    float acc[8];
#pragma unroll
    for (int kk = 0; kk < 8; ++kk) acc[kk] = 0.0f;

    // brick layout: brick = cell (x>>1,y>>1,z>>1), 64 ushort; voxel p = parity bits
    auto corner = [&](int z, int y, int x, float w) {
        int cidx = (((z >> 1) << 7) + (y >> 1)) * 128 + (x >> 1);
        int p = ((z & 1) << 2) | ((y & 1) << 1) | (x & 1);
        const uint4* v4 = reinterpret_cast<const uint4*>(vol + (size_t)cidx * 64 + p * 8);
        uint4 a = *v4; // 8 bf16
        acc[0] += w * __uint_as_float(a.x << 16);
        acc[1] += w * __uint_as_float(a.x & 0xFFFF0000u);
        acc[2] += w * __uint_as_float(a.y << 16);
        acc[3] += w * __uint_as_float(a.y & 0xFFFF0000u);
        acc[4] += w * __uint_as_float(a.z << 16);
        acc[5] += w * __uint_as_float(a.z & 0xFFFF0000u);
        acc[6] += w * __uint_as_float(a.w << 16);
        acc[7] += w * __uint_as_float(a.w & 0xFFFF0000u);
    };
    corner(z0, y0, x0, wz0 * wy0 * wx0);
    corner(z0, y0, x1, wz0 * wy0 * fx);
    corner(z0, y1, x0, wz0 * fy * wx0);
    corner(z0, y1, x1, wz0 * fy * fx);
    corner(z1, y0, x0, fz * wy0 * wx0);
    corner(z1, y0, x1, fz * wy0 * fx);
    corner(z1, y1, x0, fz * fy * wx0);
    corner(z1, y1, x1, fz * fy * fx);

    nfloat4 o0 = {acc[0], acc[1], acc[2], acc[3]};
    nfloat4 o1 = {acc[4], acc[5], acc[6], acc[7]};
    nfloat4* o4 = reinterpret_cast<nfloat4*>(out + (size_t)i * 8);
    __builtin_nontemporal_store(o0, o4);
    __builtin_nontemporal_store(o1, o4 + 1);
}

extern "C" void kernel_launch(void* const* d_in, const int* in_sizes, int n_in,
                              void* d_out, int out_size, void* d_ws, size_t ws_size,
                              hipStream_t stream) {
    const float* xyz     = (const float*)d_in[0];
    const float* approx  = (const float*)d_in[1];
    const float* detail0 = (const float*)d_in[2];
    const float* detail1 = (const float*)d_in[3];
    const float* detail2 = (const float*)d_in[4];
    float* out = (float*)d_out;
    int N = in_sizes[0] / 3;

    unsigned short* vol3 = (unsigned short*)d_ws; // 256^3 * 8 bf16 = 256 MiB (bricked)

    // Fused 3-level inverse wavelet -> brick-layout bf16 volume
    idwt_fused<<<8192, 512, 0, stream>>>(approx, detail0, detail1, detail2, vol3);
    // Trilinear sampling from bricked volume
    sample_kernel<<<(N + 255) / 256, 256, 0, stream>>>(xyz, vol3, out, N);
}